// Round 1
// baseline (1850.811 us; speedup 1.0000x reference)
//
#include <hip/hip_runtime.h>
#include <cstddef>

#define DEV_INLINE __device__ __forceinline__

constexpr int U_N = 100000;
constexpr int I_N = 50000;
constexpr int R_N = 5;
constexpr int E_N = 100000;
constexpr int K_N = 4;
constexpr int D_N = 16;
constexpr int RD_N = 64;
constexpr int OUT_N = 64;
constexpr int KF_N = 2;
constexpr float INV_TAU = 2.0f;   // 1/TAU, TAU=0.5

// workspace layout (float offsets)
constexpr size_t WS_NORM_U = 0;
constexpr size_t WS_NORM_I = WS_NORM_U + U_N;                 // 100000
constexpr size_t WS_UFEAT  = WS_NORM_I + I_N;                 // 150000
constexpr size_t WS_IFEAT  = WS_UFEAT + (size_t)U_N * D_N;    // 1,750,000
constexpr size_t WS_EAD    = WS_IFEAT + (size_t)I_N * D_N;    // 2,550,000
constexpr size_t WS_ZERO   = WS_EAD;                          // floats to zero (ead fully overwritten)

DEV_INLINE float dot4(float4 a, float4 b) { return a.x*b.x + a.y*b.y + a.z*b.z + a.w*b.w; }
DEV_INLINE void fma4(float4& a, float s, float4 w) { a.x += s*w.x; a.y += s*w.y; a.z += s*w.z; a.w += s*w.w; }
DEV_INLINE float comp(float4 v, int i) { return i == 0 ? v.x : i == 1 ? v.y : i == 2 ? v.z : v.w; }

// ---------------------------------------------------------------------------
// Phase 1: per-edge ead + degree norms (atomic).  grid = (ceil(E/256), R)
// ---------------------------------------------------------------------------
__global__ __launch_bounds__(256) void phase1_kernel(
    const float* __restrict__ user_h, const float* __restrict__ item_h,
    const float* __restrict__ user_hsum, const float* __restrict__ item_hsum,
    const float* __restrict__ review_feat, const float* __restrict__ prototypes,
    const float* __restrict__ eta,
    const int* __restrict__ rows, const int* __restrict__ cols,
    float* __restrict__ norm_u, float* __restrict__ norm_i,
    float* __restrict__ ead_ws)
{
    __shared__ __align__(16) float proto_s[K_N * RD_N];   // 256 floats
    const int tid = threadIdx.x;
    proto_s[tid] = prototypes[tid];
    __syncthreads();

    const int r = blockIdx.y;
    const int e = blockIdx.x * 256 + tid;
    if (e >= E_N) return;
    const size_t re = (size_t)r * E_N + e;
    const int row = rows[re];
    const int col = cols[re];

    // cosine similarity of user_h[r][row] . item_h[r][col]
    const float4* uh4 = (const float4*)(user_h + ((size_t)r * U_N + row) * D_N);
    const float4* ih4 = (const float4*)(item_h + ((size_t)r * I_N + col) * D_N);
    float du = 0.f, di = 0.f, dui = 0.f;
#pragma unroll
    for (int q = 0; q < 4; ++q) {
        float4 a = uh4[q], b = ih4[q];
        du += dot4(a, a); di += dot4(b, b); dui += dot4(a, b);
    }
    const float sim_k = dui / sqrtf(du * di) * INV_TAU;

    // sim_all over K  (user_hsum[r][row] . item_hsum[r][col])
    const float4* us4 = (const float4*)(user_hsum + ((size_t)r * U_N + row) * (K_N * D_N));
    const float4* is4 = (const float4*)(item_hsum + ((size_t)r * I_N + col) * (K_N * D_N));
    float ssum = 0.f;
#pragma unroll
    for (int k = 0; k < K_N; ++k) {
        float s = 0.f;
#pragma unroll
        for (int q = 0; q < 4; ++q) s += dot4(us4[k*4 + q], is4[k*4 + q]);
        ssum += expf(s * INV_TAU);
    }
    const float exp_sim = expf(sim_k) / ssum;

    // ad over K from review_feat[r][e] (256 contiguous floats) vs prototypes
    const float4* rf4 = (const float4*)(review_feat + re * (size_t)(K_N * RD_N));
    const float4* pr4 = (const float4*)proto_s;
    float adsum = 0.f, adk = 0.f;
#pragma unroll
    for (int k = 0; k < K_N; ++k) {
        float s = 0.f;
#pragma unroll
        for (int q = 0; q < RD_N / 4; ++q) s += dot4(rf4[k*(RD_N/4) + q], pr4[k*(RD_N/4) + q]);
        s *= INV_TAU;
        adsum += expf(s);
        if (k == KF_N) adk = s;
    }
    const float ead_rev = expf(adk) / adsum;

    const float g = 1.0f / (1.0f + expf(-eta[re]));
    const float ead = g * ead_rev + (1.0f - g) * exp_sim;

    ead_ws[re] = ead;
    atomicAdd(norm_u + row, ead);
    atomicAdd(norm_i + col, ead);
}

// ---------------------------------------------------------------------------
// Phase 2: w, int_dist, projected messages, scatter into feat accumulators.
// grid = (ceil(E/256), R).  Weights (10 KB) in LDS, wave-uniform broadcast.
// ---------------------------------------------------------------------------
__global__ __launch_bounds__(256) void phase2_kernel(
    const float* __restrict__ user_h, const float* __restrict__ item_h,
    const float* __restrict__ review_feat,
    const float* __restrict__ node_w_fwd, const float* __restrict__ node_w_rev,
    const float* __restrict__ review_w_fwd, const float* __restrict__ review_w_rev,
    const int* __restrict__ rows, const int* __restrict__ cols,
    const float* __restrict__ norm_u, const float* __restrict__ norm_i,
    const float* __restrict__ ead_ws,
    float* __restrict__ ufeat_acc, float* __restrict__ ifeat_acc,
    float* __restrict__ int_dist)
{
    __shared__ __align__(16) float nwf_s[D_N * D_N];
    __shared__ __align__(16) float nwr_s[D_N * D_N];
    __shared__ __align__(16) float rwf_s[RD_N * D_N];
    __shared__ __align__(16) float rwr_s[RD_N * D_N];
    const int tid = threadIdx.x;
    const int r = blockIdx.y;
    nwf_s[tid] = node_w_fwd[r * D_N * D_N + tid];
    nwr_s[tid] = node_w_rev[r * D_N * D_N + tid];
#pragma unroll
    for (int q = 0; q < 4; ++q) {
        rwf_s[q*256 + tid] = review_w_fwd[r * RD_N * D_N + q*256 + tid];
        rwr_s[q*256 + tid] = review_w_rev[r * RD_N * D_N + q*256 + tid];
    }
    __syncthreads();

    const int e = blockIdx.x * 256 + tid;
    if (e >= E_N) return;
    const size_t re = (size_t)r * E_N + e;
    const int row = rows[re];
    const int col = cols[re];

    const float w = ead_ws[re] / sqrtf(norm_u[row] * norm_i[col]);
    int_dist[re] = w;

    float4 mf[4], mr[4];
#pragma unroll
    for (int q = 0; q < 4; ++q) {
        mf[q] = make_float4(0.f, 0.f, 0.f, 0.f);
        mr[q] = make_float4(0.f, 0.f, 0.f, 0.f);
    }

    // node projections: (user_h[row]) @ node_w_fwd  and  (item_h[col]) @ node_w_rev
    const float4* uh4 = (const float4*)(user_h + ((size_t)r * U_N + row) * D_N);
    const float4* ih4 = (const float4*)(item_h + ((size_t)r * I_N + col) * D_N);
    const float4* nf4 = (const float4*)nwf_s;
    const float4* nr4 = (const float4*)nwr_s;
#pragma unroll
    for (int jq = 0; jq < 4; ++jq) {
        float4 uv = uh4[jq], iv = ih4[jq];
#pragma unroll
        for (int jj = 0; jj < 4; ++jj) {
            const int j = jq*4 + jj;
            const float uu = comp(uv, jj);
            const float ii = comp(iv, jj);
#pragma unroll
            for (int q = 0; q < 4; ++q) {
                fma4(mf[q], uu, nf4[j*4 + q]);
                fma4(mr[q], ii, nr4[j*4 + q]);
            }
        }
    }

    // review projections: rf_k @ review_w_{fwd,rev}  (rf_k = review_feat[r,e,KF,:])
    const float4* rfk4 = (const float4*)(review_feat + re * (size_t)(K_N * RD_N) + KF_N * RD_N);
    const float4* rf4w = (const float4*)rwf_s;
    const float4* rr4w = (const float4*)rwr_s;
#pragma unroll
    for (int jq = 0; jq < 16; ++jq) {
        float4 v4 = rfk4[jq];
#pragma unroll
        for (int jj = 0; jj < 4; ++jj) {
            const int j = jq*4 + jj;
            const float v = comp(v4, jj);
#pragma unroll
            for (int q = 0; q < 4; ++q) {
                fma4(mf[q], v, rf4w[j*4 + q]);
                fma4(mr[q], v, rr4w[j*4 + q]);
            }
        }
    }

    float* ip = ifeat_acc + (size_t)col * D_N;
    float* up = ufeat_acc + (size_t)row * D_N;
#pragma unroll
    for (int q = 0; q < 4; ++q) {
        atomicAdd(ip + q*4 + 0, mf[q].x * w);
        atomicAdd(ip + q*4 + 1, mf[q].y * w);
        atomicAdd(ip + q*4 + 2, mf[q].z * w);
        atomicAdd(ip + q*4 + 3, mf[q].w * w);
        atomicAdd(up + q*4 + 0, mr[q].x * w);
        atomicAdd(up + q*4 + 1, mr[q].y * w);
        atomicAdd(up + q*4 + 2, mr[q].z * w);
        atomicAdd(up + q*4 + 3, mr[q].w * w);
    }
}

// ---------------------------------------------------------------------------
// Phase 3: leaky-ReLU + (N x 16) @ (16 x 64) + bias.  4 outputs per thread.
// ---------------------------------------------------------------------------
__global__ __launch_bounds__(256) void fc_kernel(
    const float* __restrict__ acc, const float* __restrict__ W,
    const float* __restrict__ bias, float* __restrict__ out, int n)
{
    __shared__ __align__(16) float w_s[D_N * OUT_N];   // 1024 floats
    __shared__ __align__(16) float b_s[OUT_N];
    const int tid = threadIdx.x;
#pragma unroll
    for (int q = 0; q < 4; ++q) w_s[q*256 + tid] = W[q*256 + tid];
    if (tid < OUT_N) b_s[tid] = bias[tid];
    __syncthreads();

    const int gid = blockIdx.x * 256 + tid;
    if (gid >= n * (OUT_N / 4)) return;
    const int u  = gid >> 4;          // OUT_N/4 = 16 threads per row
    const int oc = (gid & 15) * 4;

    const float4* a4 = (const float4*)(acc + (size_t)u * D_N);
    float4 s = *(const float4*)(b_s + oc);
#pragma unroll
    for (int dq = 0; dq < 4; ++dq) {
        float4 av = a4[dq];
#pragma unroll
        for (int jj = 0; jj < 4; ++jj) {
            const int d = dq*4 + jj;
            float x = comp(av, jj);
            x = (x >= 0.f) ? x : 0.1f * x;   // leaky relu
            fma4(s, x, *(const float4*)(w_s + d*OUT_N + oc));
        }
    }
    *((float4*)(out + (size_t)u * OUT_N + oc)) = s;
}

// ---------------------------------------------------------------------------
extern "C" void kernel_launch(void* const* d_in, const int* in_sizes, int n_in,
                              void* d_out, int out_size, void* d_ws, size_t ws_size,
                              hipStream_t stream)
{
    const float* user_h       = (const float*)d_in[0];
    const float* item_h       = (const float*)d_in[1];
    const float* user_hsum    = (const float*)d_in[2];
    const float* item_hsum    = (const float*)d_in[3];
    const float* review_feat  = (const float*)d_in[4];
    const float* prototypes   = (const float*)d_in[5];
    const float* eta          = (const float*)d_in[6];
    const float* node_w_fwd   = (const float*)d_in[7];
    const float* node_w_rev   = (const float*)d_in[8];
    const float* review_w_fwd = (const float*)d_in[9];
    const float* review_w_rev = (const float*)d_in[10];
    const float* ufc_w        = (const float*)d_in[11];
    const float* ufc_b        = (const float*)d_in[12];
    const float* ifc_w        = (const float*)d_in[13];
    const float* ifc_b        = (const float*)d_in[14];
    const int*   rows         = (const int*)d_in[15];
    const int*   cols         = (const int*)d_in[16];

    float* ws  = (float*)d_ws;
    float* out = (float*)d_out;

    // zero norm_u, norm_i, ufeat_acc, ifeat_acc (ead region fully overwritten)
    hipMemsetAsync(ws, 0, WS_ZERO * sizeof(float), stream);

    const dim3 blk(256);
    const dim3 g_edge((E_N + 255) / 256, R_N);

    phase1_kernel<<<g_edge, blk, 0, stream>>>(
        user_h, item_h, user_hsum, item_hsum, review_feat, prototypes, eta,
        rows, cols, ws + WS_NORM_U, ws + WS_NORM_I, ws + WS_EAD);

    float* int_dist_out = out + (size_t)U_N * OUT_N + (size_t)I_N * OUT_N;
    phase2_kernel<<<g_edge, blk, 0, stream>>>(
        user_h, item_h, review_feat,
        node_w_fwd, node_w_rev, review_w_fwd, review_w_rev, rows, cols,
        ws + WS_NORM_U, ws + WS_NORM_I, ws + WS_EAD,
        ws + WS_UFEAT, ws + WS_IFEAT, int_dist_out);

    fc_kernel<<<dim3((U_N * (OUT_N/4) + 255) / 256), blk, 0, stream>>>(
        ws + WS_UFEAT, ufc_w, ufc_b, out, U_N);
    fc_kernel<<<dim3((I_N * (OUT_N/4) + 255) / 256), blk, 0, stream>>>(
        ws + WS_IFEAT, ifc_w, ifc_b, out + (size_t)U_N * OUT_N, I_N);
}

// Round 2
// 1145.660 us; speedup vs baseline: 1.6155x; 1.6155x over previous
//
#include <hip/hip_runtime.h>
#include <cstddef>

#define DEV_INLINE __device__ __forceinline__

constexpr int U_N = 100000;
constexpr int I_N = 50000;
constexpr int R_N = 5;
constexpr int E_N = 100000;
constexpr int K_N = 4;
constexpr int D_N = 16;
constexpr int RD_N = 64;
constexpr int OUT_N = 64;
constexpr int KF_N = 2;
constexpr float INV_TAU = 2.0f;   // 1/TAU, TAU=0.5

constexpr int NE_TOT = R_N * E_N;        // 500000 edges
constexpr int NNODE  = U_N + I_N;        // 150000 nodes (users then items)
constexpr int NB_SCAN = (NNODE + 255) / 256;   // 586 scan blocks

// workspace layout in 4-byte elements (all float4 bases are %4==0)
constexpr size_t OFS_CNT    = 0;                        // NNODE ints
constexpr size_t OFS_OFF    = 150000;                   // NNODE+1 ints
constexpr size_t OFS_BSUMS  = 300016;                   // 1024 ints
constexpr size_t OFS_CURSOR = 301040;                   // NNODE ints
constexpr size_t OFS_LIST   = 451040;                   // 2*NE_TOT ints
constexpr size_t OFS_EAD    = 1451040;                  // NE_TOT floats
constexpr size_t OFS_NORM   = 1951040;                  // NNODE floats
constexpr size_t OFS_MFWD   = 2101040;                  // NE_TOT*16 floats
constexpr size_t OFS_MREV   = 10101040;                 // NE_TOT*16 floats
constexpr size_t OFS_UFEAT  = 18101040;                 // U_N*16 floats
constexpr size_t OFS_IFEAT  = 19701040;                 // I_N*16 floats
// total = 20,501,040 elems = 82.0 MB

DEV_INLINE float dot4(float4 a, float4 b) { return a.x*b.x + a.y*b.y + a.z*b.z + a.w*b.w; }
DEV_INLINE void fma4(float4& a, float s, float4 w) { a.x += s*w.x; a.y += s*w.y; a.z += s*w.z; a.w += s*w.w; }
DEV_INLINE float comp(float4 v, int i) { return i == 0 ? v.x : i == 1 ? v.y : i == 2 ? v.z : v.w; }

// ---------------------------------------------------------------------------
// CSR build: count -> scan(3) -> fill
// ---------------------------------------------------------------------------
__global__ __launch_bounds__(256) void count_kernel(
    const int* __restrict__ rows, const int* __restrict__ cols, int* __restrict__ cnt)
{
    const int idx = blockIdx.x * 256 + threadIdx.x;
    if (idx >= NE_TOT) return;
    atomicAdd(cnt + rows[idx], 1);
    atomicAdd(cnt + U_N + cols[idx], 1);
}

__global__ __launch_bounds__(256) void scan1_kernel(
    const int* __restrict__ cnt, int* __restrict__ off, int* __restrict__ bsums)
{
    __shared__ int s[256];
    const int t = threadIdx.x;
    const int i = blockIdx.x * 256 + t;
    const int v = (i < NNODE) ? cnt[i] : 0;
    s[t] = v;
    __syncthreads();
#pragma unroll
    for (int d = 1; d < 256; d <<= 1) {
        const int x = (t >= d) ? s[t - d] : 0;
        __syncthreads();
        s[t] += x;
        __syncthreads();
    }
    if (i < NNODE) off[i] = s[t] - v;          // block-local exclusive
    if (t == 255) bsums[blockIdx.x] = s[255];  // block total
}

__global__ __launch_bounds__(1024) void scan2_kernel(int* __restrict__ bsums)
{
    __shared__ int s[1024];
    const int t = threadIdx.x;
    const int v = (t < NB_SCAN) ? bsums[t] : 0;
    s[t] = v;
    __syncthreads();
#pragma unroll
    for (int d = 1; d < 1024; d <<= 1) {
        const int x = (t >= d) ? s[t - d] : 0;
        __syncthreads();
        s[t] += x;
        __syncthreads();
    }
    if (t < NB_SCAN) bsums[t] = s[t] - v;      // exclusive block offsets
}

__global__ __launch_bounds__(256) void scan3_kernel(
    int* __restrict__ off, const int* __restrict__ bsums, int* __restrict__ cursor)
{
    const int i = blockIdx.x * 256 + threadIdx.x;
    if (i < NNODE) {
        const int v = off[i] + bsums[i >> 8];
        off[i] = v;
        cursor[i] = v;
    }
    if (i == 0) off[NNODE] = 2 * NE_TOT;
}

__global__ __launch_bounds__(256) void fill_kernel(
    const int* __restrict__ rows, const int* __restrict__ cols,
    int* __restrict__ cursor, int* __restrict__ list)
{
    const int idx = blockIdx.x * 256 + threadIdx.x;
    if (idx >= NE_TOT) return;
    const int p = atomicAdd(cursor + rows[idx], 1);
    list[p] = idx;
    const int q = atomicAdd(cursor + U_N + cols[idx], 1);
    list[q] = idx;
}

// ---------------------------------------------------------------------------
// Phase 1: per-edge ead, quad-split (4 lanes per edge). No atomics.
// grid = (ceil(E*4/256), R)
// ---------------------------------------------------------------------------
__global__ __launch_bounds__(256) void phase1_kernel(
    const float* __restrict__ user_h, const float* __restrict__ item_h,
    const float* __restrict__ user_hsum, const float* __restrict__ item_hsum,
    const float* __restrict__ review_feat, const float* __restrict__ prototypes,
    const float* __restrict__ eta,
    const int* __restrict__ rows, const int* __restrict__ cols,
    float* __restrict__ ead_ws)
{
    __shared__ __align__(16) float proto_s[K_N * RD_N];   // 256 floats
    const int tid = threadIdx.x;
    proto_s[tid] = prototypes[tid];
    __syncthreads();

    const int r = blockIdx.y;
    const int e = blockIdx.x * 64 + (tid >> 2);
    const int l = tid & 3;
    if (e >= E_N) return;
    const size_t re = (size_t)r * E_N + e;
    const int row = rows[re];
    const int col = cols[re];

    // cosine sim: each lane one float4 of the 16-vector, quad reduce
    const float4* uh4 = (const float4*)(user_h + ((size_t)r * U_N + row) * D_N);
    const float4* ih4 = (const float4*)(item_h + ((size_t)r * I_N + col) * D_N);
    const float4 a = uh4[l], b = ih4[l];
    float du = dot4(a, a), di = dot4(b, b), dui = dot4(a, b);
    du  += __shfl_xor(du, 1);  du  += __shfl_xor(du, 2);
    di  += __shfl_xor(di, 1);  di  += __shfl_xor(di, 2);
    dui += __shfl_xor(dui, 1); dui += __shfl_xor(dui, 2);
    const float sim_k = dui / sqrtf(du * di) * INV_TAU;

    // sim_all: lane l handles k=l (64B chunk of the 256B row)
    const float4* us4 = (const float4*)(user_hsum + ((size_t)r * U_N + row) * (K_N * D_N)) + l * 4;
    const float4* is4 = (const float4*)(item_hsum + ((size_t)r * I_N + col) * (K_N * D_N)) + l * 4;
    float s = 0.f;
#pragma unroll
    for (int q = 0; q < 4; ++q) s += dot4(us4[q], is4[q]);
    float ssum = expf(s * INV_TAU);
    ssum += __shfl_xor(ssum, 1); ssum += __shfl_xor(ssum, 2);
    const float exp_sim = expf(sim_k) / ssum;

    // ad: lane l handles k=l (256B chunk of the 1KB review row)
    const float4* rf4 = (const float4*)(review_feat + re * (size_t)(K_N * RD_N)) + l * 16;
    const float4* pr4 = (const float4*)proto_s + l * 16;
    float t = 0.f;
#pragma unroll
    for (int q = 0; q < 16; ++q) t += dot4(rf4[q], pr4[q]);
    t *= INV_TAU;
    float adsum = expf(t);
    adsum += __shfl_xor(adsum, 1); adsum += __shfl_xor(adsum, 2);
    const float adk = __shfl(t, KF_N, 4);
    const float ead_rev = expf(adk) / adsum;

    const float g = 1.0f / (1.0f + expf(-eta[re]));
    const float ead = g * ead_rev + (1.0f - g) * exp_sim;
    if (l == 0) ead_ws[re] = ead;
}

// ---------------------------------------------------------------------------
// Norm gather: per node, sum ead over incident edges. No atomics.
// ---------------------------------------------------------------------------
__global__ __launch_bounds__(256) void norm_kernel(
    const int* __restrict__ off, const int* __restrict__ list,
    const float* __restrict__ ead, float* __restrict__ norm)
{
    const int n = blockIdx.x * 256 + threadIdx.x;
    if (n >= NNODE) return;
    const int p0 = off[n], p1 = off[n + 1];
    float acc = 0.f;
    for (int p = p0; p < p1; ++p) acc += ead[list[p]];
    norm[n] = acc;
}

// ---------------------------------------------------------------------------
// Phase 2: per-edge messages, written sequentially (no atomics).
// grid = (ceil(E/256), R)
// ---------------------------------------------------------------------------
__global__ __launch_bounds__(256) void phase2_kernel(
    const float* __restrict__ user_h, const float* __restrict__ item_h,
    const float* __restrict__ review_feat,
    const float* __restrict__ node_w_fwd, const float* __restrict__ node_w_rev,
    const float* __restrict__ review_w_fwd, const float* __restrict__ review_w_rev,
    const int* __restrict__ rows, const int* __restrict__ cols,
    const float* __restrict__ norm, const float* __restrict__ ead_ws,
    float* __restrict__ m_fwd, float* __restrict__ m_rev,
    float* __restrict__ int_dist)
{
    __shared__ __align__(16) float nwf_s[D_N * D_N];
    __shared__ __align__(16) float nwr_s[D_N * D_N];
    __shared__ __align__(16) float rwf_s[RD_N * D_N];
    __shared__ __align__(16) float rwr_s[RD_N * D_N];
    const int tid = threadIdx.x;
    const int r = blockIdx.y;
    nwf_s[tid] = node_w_fwd[r * D_N * D_N + tid];
    nwr_s[tid] = node_w_rev[r * D_N * D_N + tid];
#pragma unroll
    for (int q = 0; q < 4; ++q) {
        rwf_s[q*256 + tid] = review_w_fwd[r * RD_N * D_N + q*256 + tid];
        rwr_s[q*256 + tid] = review_w_rev[r * RD_N * D_N + q*256 + tid];
    }
    __syncthreads();

    const int e = blockIdx.x * 256 + tid;
    if (e >= E_N) return;
    const size_t re = (size_t)r * E_N + e;
    const int row = rows[re];
    const int col = cols[re];

    const float w = ead_ws[re] / sqrtf(norm[row] * norm[U_N + col]);
    int_dist[re] = w;

    float4 mf[4], mr[4];
#pragma unroll
    for (int q = 0; q < 4; ++q) {
        mf[q] = make_float4(0.f, 0.f, 0.f, 0.f);
        mr[q] = make_float4(0.f, 0.f, 0.f, 0.f);
    }

    const float4* uh4 = (const float4*)(user_h + ((size_t)r * U_N + row) * D_N);
    const float4* ih4 = (const float4*)(item_h + ((size_t)r * I_N + col) * D_N);
    const float4* nf4 = (const float4*)nwf_s;
    const float4* nr4 = (const float4*)nwr_s;
#pragma unroll
    for (int jq = 0; jq < 4; ++jq) {
        float4 uv = uh4[jq], iv = ih4[jq];
#pragma unroll
        for (int jj = 0; jj < 4; ++jj) {
            const int j = jq*4 + jj;
            const float uu = comp(uv, jj);
            const float ii = comp(iv, jj);
#pragma unroll
            for (int q = 0; q < 4; ++q) {
                fma4(mf[q], uu, nf4[j*4 + q]);
                fma4(mr[q], ii, nr4[j*4 + q]);
            }
        }
    }

    const float4* rfk4 = (const float4*)(review_feat + re * (size_t)(K_N * RD_N) + KF_N * RD_N);
    const float4* rf4w = (const float4*)rwf_s;
    const float4* rr4w = (const float4*)rwr_s;
#pragma unroll
    for (int jq = 0; jq < 16; ++jq) {
        float4 v4 = rfk4[jq];
#pragma unroll
        for (int jj = 0; jj < 4; ++jj) {
            const int j = jq*4 + jj;
            const float v = comp(v4, jj);
#pragma unroll
            for (int q = 0; q < 4; ++q) {
                fma4(mf[q], v, rf4w[j*4 + q]);
                fma4(mr[q], v, rr4w[j*4 + q]);
            }
        }
    }

    float4* mfp = (float4*)(m_fwd + re * (size_t)D_N);
    float4* mrp = (float4*)(m_rev + re * (size_t)D_N);
#pragma unroll
    for (int q = 0; q < 4; ++q) {
        float4 f = mf[q], g2 = mr[q];
        f.x *= w; f.y *= w; f.z *= w; f.w *= w;
        g2.x *= w; g2.y *= w; g2.z *= w; g2.w *= w;
        mfp[q] = f;
        mrp[q] = g2;
    }
}

// ---------------------------------------------------------------------------
// Feature gather: 4 lanes per node, each sums one float4 slice. No atomics.
// Users gather m_rev (from incident edges); items gather m_fwd.
// ---------------------------------------------------------------------------
__global__ __launch_bounds__(256) void gather_kernel(
    const int* __restrict__ off, const int* __restrict__ list,
    const float* __restrict__ m_fwd, const float* __restrict__ m_rev,
    float* __restrict__ ufeat, float* __restrict__ ifeat)
{
    const int gid = blockIdx.x * 256 + threadIdx.x;
    const int n = gid >> 2;
    const int l = gid & 3;
    if (n >= NNODE) return;
    const int p0 = off[n], p1 = off[n + 1];
    const float* __restrict__ src = (n < U_N) ? m_rev : m_fwd;
    float4 acc = make_float4(0.f, 0.f, 0.f, 0.f);
    for (int p = p0; p < p1; ++p) {
        const float4 v = *((const float4*)(src + (size_t)list[p] * D_N) + l);
        acc.x += v.x; acc.y += v.y; acc.z += v.z; acc.w += v.w;
    }
    float* dst = (n < U_N) ? (ufeat + (size_t)n * D_N) : (ifeat + (size_t)(n - U_N) * D_N);
    *((float4*)dst + l) = acc;
}

// ---------------------------------------------------------------------------
// FC: leaky-ReLU + (N x 16) @ (16 x 64) + bias.  4 outputs per thread.
// ---------------------------------------------------------------------------
__global__ __launch_bounds__(256) void fc_kernel(
    const float* __restrict__ acc, const float* __restrict__ W,
    const float* __restrict__ bias, float* __restrict__ out, int n)
{
    __shared__ __align__(16) float w_s[D_N * OUT_N];
    __shared__ __align__(16) float b_s[OUT_N];
    const int tid = threadIdx.x;
#pragma unroll
    for (int q = 0; q < 4; ++q) w_s[q*256 + tid] = W[q*256 + tid];
    if (tid < OUT_N) b_s[tid] = bias[tid];
    __syncthreads();

    const int gid = blockIdx.x * 256 + tid;
    if (gid >= n * (OUT_N / 4)) return;
    const int u  = gid >> 4;
    const int oc = (gid & 15) * 4;

    const float4* a4 = (const float4*)(acc + (size_t)u * D_N);
    float4 s = *(const float4*)(b_s + oc);
#pragma unroll
    for (int dq = 0; dq < 4; ++dq) {
        float4 av = a4[dq];
#pragma unroll
        for (int jj = 0; jj < 4; ++jj) {
            const int d = dq*4 + jj;
            float x = comp(av, jj);
            x = (x >= 0.f) ? x : 0.1f * x;
            fma4(s, x, *(const float4*)(w_s + d*OUT_N + oc));
        }
    }
    *((float4*)(out + (size_t)u * OUT_N + oc)) = s;
}

// ---------------------------------------------------------------------------
extern "C" void kernel_launch(void* const* d_in, const int* in_sizes, int n_in,
                              void* d_out, int out_size, void* d_ws, size_t ws_size,
                              hipStream_t stream)
{
    const float* user_h       = (const float*)d_in[0];
    const float* item_h       = (const float*)d_in[1];
    const float* user_hsum    = (const float*)d_in[2];
    const float* item_hsum    = (const float*)d_in[3];
    const float* review_feat  = (const float*)d_in[4];
    const float* prototypes   = (const float*)d_in[5];
    const float* eta          = (const float*)d_in[6];
    const float* node_w_fwd   = (const float*)d_in[7];
    const float* node_w_rev   = (const float*)d_in[8];
    const float* review_w_fwd = (const float*)d_in[9];
    const float* review_w_rev = (const float*)d_in[10];
    const float* ufc_w        = (const float*)d_in[11];
    const float* ufc_b        = (const float*)d_in[12];
    const float* ifc_w        = (const float*)d_in[13];
    const float* ifc_b        = (const float*)d_in[14];
    const int*   rows         = (const int*)d_in[15];
    const int*   cols         = (const int*)d_in[16];

    int*   wsi = (int*)d_ws;
    float* wsf = (float*)d_ws;
    float* out = (float*)d_out;

    int*   cnt    = wsi + OFS_CNT;
    int*   off    = wsi + OFS_OFF;
    int*   bsums  = wsi + OFS_BSUMS;
    int*   cursor = wsi + OFS_CURSOR;
    int*   list   = wsi + OFS_LIST;
    float* ead    = wsf + OFS_EAD;
    float* norm   = wsf + OFS_NORM;
    float* m_fwd  = wsf + OFS_MFWD;
    float* m_rev  = wsf + OFS_MREV;
    float* ufeat  = wsf + OFS_UFEAT;
    float* ifeat  = wsf + OFS_IFEAT;

    hipMemsetAsync(cnt, 0, NNODE * sizeof(int), stream);

    const dim3 blk(256);
    const dim3 g_e((NE_TOT + 255) / 256);

    count_kernel<<<g_e, blk, 0, stream>>>(rows, cols, cnt);
    scan1_kernel<<<dim3(NB_SCAN), blk, 0, stream>>>(cnt, off, bsums);
    scan2_kernel<<<dim3(1), dim3(1024), 0, stream>>>(bsums);
    scan3_kernel<<<dim3((NNODE + 255) / 256), blk, 0, stream>>>(off, bsums, cursor);
    fill_kernel<<<g_e, blk, 0, stream>>>(rows, cols, cursor, list);

    phase1_kernel<<<dim3((E_N * 4 + 255) / 256, R_N), blk, 0, stream>>>(
        user_h, item_h, user_hsum, item_hsum, review_feat, prototypes, eta,
        rows, cols, ead);

    norm_kernel<<<dim3((NNODE + 255) / 256), blk, 0, stream>>>(off, list, ead, norm);

    float* int_dist_out = out + (size_t)U_N * OUT_N + (size_t)I_N * OUT_N;
    phase2_kernel<<<dim3((E_N + 255) / 256, R_N), blk, 0, stream>>>(
        user_h, item_h, review_feat,
        node_w_fwd, node_w_rev, review_w_fwd, review_w_rev, rows, cols,
        norm, ead, m_fwd, m_rev, int_dist_out);

    gather_kernel<<<dim3((NNODE * 4 + 255) / 256), blk, 0, stream>>>(
        off, list, m_fwd, m_rev, ufeat, ifeat);

    fc_kernel<<<dim3((U_N * (OUT_N/4) + 255) / 256), blk, 0, stream>>>(
        ufeat, ufc_w, ufc_b, out, U_N);
    fc_kernel<<<dim3((I_N * (OUT_N/4) + 255) / 256), blk, 0, stream>>>(
        ifeat, ifc_w, ifc_b, out + (size_t)U_N * OUT_N, I_N);
}